// Round 3
// baseline (384.595 us; speedup 1.0000x reference)
//
#include <hip/hip_runtime.h>
#include <math.h>

#define CH 512
#define PLANE 4096   // 64*64
#define EPS 1e-5f
#define PITCH 68     // LDS plane pitch in floats: %4==0 (b128-aligned), %32==4 (bank spread)

__device__ __forceinline__ float leaky(float x) { return x >= 0.f ? x : 0.01f * x; }

__device__ __forceinline__ float wave_sum(float v) {
    #pragma unroll
    for (int off = 32; off; off >>= 1) v += __shfl_xor(v, off, 64);
    return v;
}

// ---------------- Kernel 1: fused predictor ----------------
// grid = 16 n * 8 chunks = 128 blocks, 256 threads
__global__ __launch_bounds__(256) void predictor_kernel(
    const float* __restrict__ style,   // [N,512,4,4]
    const float* __restrict__ dw_w,    // [8,512,2,2]
    const float* __restrict__ dw_b,    // [8]
    const float* __restrict__ pk_w,    // [8,512]
    const float* __restrict__ pk_b,    // [8]
    const float* __restrict__ pb_w,    // [512,512]
    const float* __restrict__ pb_b,    // [512]
    float* __restrict__ d_pred,        // [N,72]
    float* __restrict__ S_out,         // [N]
    float* __restrict__ bias_out)      // [N,512]
{
    const int blk = blockIdx.x;
    const int n = blk >> 3, chunk = blk & 7;
    const int t = threadIdx.x, lane = t & 63, w = t >> 6;
    __shared__ float s_style[8192];   // 32 KB
    __shared__ float s_sd[512];

    const float4* sp = (const float4*)(style + (size_t)n * 8192);
    float4* lp = (float4*)s_style;
    #pragma unroll
    for (int i = 0; i < 8; ++i) lp[t + 256 * i] = sp[t + 256 * i];
    __syncthreads();

    for (int c = t; c < 512; c += 256) {
        const float* q = s_style + c * 16;
        float s = 0.f;
        #pragma unroll
        for (int k = 0; k < 16; ++k) s += q[k];
        s_sd[c] = s * (1.f / 16.f);
    }
    __syncthreads();

    if (chunk == 0) {
        // d_pred: 72 taps, 18 per wave, lane-parallel over 512 channels
        for (int k = 0; k < 18; ++k) {
            int r = w * 18 + k;
            int j = r / 9, pos = r % 9, y = pos / 3, x = pos % 3;
            float acc = 0.f;
            #pragma unroll
            for (int i = 0; i < 8; ++i) {
                int c = lane + 64 * i;
                float4 wv = ((const float4*)dw_w)[j * 512 + c];
                const float* s = s_style + c * 16 + y * 4 + x;
                acc += s[0] * wv.x + s[1] * wv.y + s[4] * wv.z + s[5] * wv.w;
            }
            acc = wave_sum(acc);
            if (lane == 0) d_pred[n * 72 + r] = leaky(acc + dw_b[j]);
        }
    }
    if (chunk == 1 && w == 0) {
        float Ssum = 0.f;
        #pragma unroll
        for (int o = 0; o < 8; ++o) {
            float acc = 0.f;
            #pragma unroll
            for (int i = 0; i < 8; ++i) {
                int c = lane + 64 * i;
                acc += pk_w[o * 512 + c] * s_sd[c];
            }
            Ssum += wave_sum(acc) + pk_b[o];
        }
        if (lane == 0) S_out[n] = Ssum;
    }
    // bias GEMV: this chunk's 64 channels, one channel at a time per wave
    #pragma unroll 1
    for (int i = 0; i < 16; ++i) {
        int c = chunk * 64 + w * 16 + i;
        float acc = 0.f;
        #pragma unroll
        for (int q = 0; q < 8; ++q) {
            int cc = lane + 64 * q;
            acc += pb_w[(size_t)c * 512 + cc] * s_sd[cc];
        }
        acc = wave_sum(acc);
        if (lane == 0) bias_out[n * 512 + c] = acc + pb_b[c];
    }
}

// ---------------- Kernel 2: one-pass fused stats + conv + pointwise + IN ----------------
// one block per (n,g); 256 threads; each thread owns a 4x4 patch of all 8 channels.
__global__ __launch_bounds__(256, 2) void fused_kernel(
    const float* __restrict__ content,   // [N,512,64,64]
    const float* __restrict__ d_pred,    // [N,72]
    const float* __restrict__ S_in,      // [N]
    const float* __restrict__ bias_in,   // [N,512]
    float* __restrict__ out)             // [N,512,64,64]
{
    const int b = blockIdx.x;
    const int n = b >> 6, g = b & 63;
    const int t = threadIdx.x, lane = t & 63, wv = t >> 6;
    const int r0 = (t >> 4) * 4;     // patch row base
    const int c0 = (t & 15) * 4;     // patch col base

    __shared__ float s_plane[2][64 * PITCH];   // 2 x 17 KB double buffer
    __shared__ float s_d[72];
    __shared__ float s_misc[9];                // S, bias[8]
    __shared__ float s_red[4][16];             // per-wave: s[8], sq[8]
    __shared__ float s_ms[16];                 // mean[8], rstd[8]

    if (t < 72) s_d[t] = d_pred[n * 72 + t];
    if (t == 72) s_misc[0] = S_in[n];
    if (t >= 80 && t < 88) s_misc[1 + t - 80] = bias_in[n * 512 + g * 8 + (t - 80)];

    // ---- load all 8 planes (own 4x4 patch) : 32 coalesced float4 loads ----
    const float4* cb = (const float4*)(content + (size_t)(n * 512 + g * 8) * PLANE);
    float4 x[8][4];
    #pragma unroll
    for (int j = 0; j < 8; ++j)
        #pragma unroll
        for (int i = 0; i < 4; ++i)
            x[j][i] = cb[j * 1024 + (r0 + i) * 16 + (t & 15)];

    // ---- per-channel partial stats from registers ----
    float s[8], sq[8];
    #pragma unroll
    for (int j = 0; j < 8; ++j) {
        float a = 0.f, q = 0.f;
        #pragma unroll
        for (int i = 0; i < 4; ++i) {
            float4 v = x[j][i];
            a += v.x + v.y + v.z + v.w;
            q += v.x * v.x + v.y * v.y + v.z * v.z + v.w * v.w;
        }
        s[j] = a; sq[j] = q;
    }

    // ---- conv: accumulate group depthwise response D over 8 channels ----
    const int rm1 = (r0 == 0)  ? 1  : r0 - 1;
    const int rp4 = (r0 == 60) ? 62 : r0 + 4;
    const int cm1 = (c0 == 0)  ? 1  : c0 - 1;
    const int cp4 = (c0 == 60) ? 62 : c0 + 4;

    float D[4][4];
    #pragma unroll
    for (int i = 0; i < 4; ++i)
        #pragma unroll
        for (int k = 0; k < 4; ++k) D[i][k] = 0.f;

    #pragma unroll 1
    for (int j = 0; j < 8; ++j) {
        float* buf = s_plane[j & 1];
        #pragma unroll
        for (int i = 0; i < 4; ++i)
            *(float4*)(buf + (r0 + i) * PITCH + c0) = x[j][i];
        __syncthreads();

        // 6x6 window: inner 4x4 from regs, halo from LDS (reflect-filled)
        float V[6][6];
        #pragma unroll
        for (int i = 0; i < 4; ++i) {
            V[1 + i][1] = x[j][i].x; V[1 + i][2] = x[j][i].y;
            V[1 + i][3] = x[j][i].z; V[1 + i][4] = x[j][i].w;
            V[1 + i][0] = buf[(r0 + i) * PITCH + cm1];
            V[1 + i][5] = buf[(r0 + i) * PITCH + cp4];
        }
        {
            float4 topv = *(const float4*)(buf + rm1 * PITCH + c0);
            V[0][1] = topv.x; V[0][2] = topv.y; V[0][3] = topv.z; V[0][4] = topv.w;
            V[0][0] = buf[rm1 * PITCH + cm1];
            V[0][5] = buf[rm1 * PITCH + cp4];
            float4 botv = *(const float4*)(buf + rp4 * PITCH + c0);
            V[5][1] = botv.x; V[5][2] = botv.y; V[5][3] = botv.z; V[5][4] = botv.w;
            V[5][0] = buf[rp4 * PITCH + cm1];
            V[5][5] = buf[rp4 * PITCH + cp4];
        }

        #pragma unroll
        for (int ky = 0; ky < 3; ++ky)
            #pragma unroll
            for (int kx = 0; kx < 3; ++kx) {
                float wgt = s_d[j * 9 + ky * 3 + kx];
                #pragma unroll
                for (int i = 0; i < 4; ++i)
                    #pragma unroll
                    for (int k = 0; k < 4; ++k)
                        D[i][k] += wgt * V[i + ky][k + kx];
            }
    }

    // ---- finish instance-norm stats (block reduce) ----
    #pragma unroll
    for (int j = 0; j < 8; ++j) { s[j] = wave_sum(s[j]); sq[j] = wave_sum(sq[j]); }
    if (lane == 0) {
        #pragma unroll
        for (int j = 0; j < 8; ++j) { s_red[wv][j] = s[j]; s_red[wv][8 + j] = sq[j]; }
    }
    __syncthreads();
    if (t < 8) {
        float S = s_red[0][t] + s_red[1][t] + s_red[2][t] + s_red[3][t];
        float Q = s_red[0][8 + t] + s_red[1][8 + t] + s_red[2][8 + t] + s_red[3][8 + t];
        float m = S * (1.f / 4096.f);
        float var = (Q - 4096.f * m * m) * (1.f / 4095.f);   // ddof=1
        s_ms[t] = m;
        s_ms[8 + t] = rsqrtf(var + EPS);
    }
    __syncthreads();

    // ---- epilogue: out = norm(x) * leaky(D*S + bias) ----
    const float Ssc = s_misc[0];
    float4* ob = (float4*)(out + (size_t)(n * 512 + g * 8) * PLANE);
    #pragma unroll
    for (int j = 0; j < 8; ++j) {
        float m = s_ms[j], rs = s_ms[8 + j], bb = s_misc[1 + j];
        #pragma unroll
        for (int i = 0; i < 4; ++i) {
            float4 r;
            r.x = (x[j][i].x - m) * rs * leaky(D[i][0] * Ssc + bb);
            r.y = (x[j][i].y - m) * rs * leaky(D[i][1] * Ssc + bb);
            r.z = (x[j][i].z - m) * rs * leaky(D[i][2] * Ssc + bb);
            r.w = (x[j][i].w - m) * rs * leaky(D[i][3] * Ssc + bb);
            ob[j * 1024 + (r0 + i) * 16 + (t & 15)] = r;
        }
    }
}

extern "C" void kernel_launch(void* const* d_in, const int* in_sizes, int n_in,
                              void* d_out, int out_size, void* d_ws, size_t ws_size,
                              hipStream_t stream) {
    const float* style   = (const float*)d_in[0];
    const float* content = (const float*)d_in[1];
    const float* dw_w    = (const float*)d_in[2];
    const float* dw_b    = (const float*)d_in[3];
    const float* pk_w    = (const float*)d_in[4];
    const float* pk_b    = (const float*)d_in[5];
    const float* pb_w    = (const float*)d_in[6];
    const float* pb_b    = (const float*)d_in[7];
    float* out = (float*)d_out;
    float* ws  = (float*)d_ws;

    const int N = 16;
    float* d_pred  = ws;                  // N*72
    float* S_ws    = d_pred + N * 72;     // N
    float* bias_ws = S_ws + N;            // N*512

    predictor_kernel<<<N * 8, 256, 0, stream>>>(style, dw_w, dw_b, pk_w, pk_b,
                                                pb_w, pb_b, d_pred, S_ws, bias_ws);
    fused_kernel<<<N * 64, 256, 0, stream>>>(content, d_pred, S_ws, bias_ws, out);
}